// Round 3
// baseline (104.648 us; speedup 1.0000x reference)
//
#include <hip/hip_runtime.h>
#include <math.h>

#define B_   8
#define T_   128
#define C_   256
#define M_   1024          // B_*T_ = GEMM M (rows of x, flat [b*128+t])
#define NO   2304          // GEMM N per side = 256 o * 9 taps
#define LDP  136           // LDS half-tile row stride in ushorts (128 + 8 pad)

typedef unsigned short ushort;
typedef ushort ushort8v __attribute__((ext_vector_type(8)));
typedef __bf16 bf16x8  __attribute__((ext_vector_type(8)));
typedef float  f32x4   __attribute__((ext_vector_type(4)));

__device__ __forceinline__ ushort f2bf(float f) {
    unsigned u = __float_as_uint(f);
    u += 0x7fffu + ((u >> 16) & 1u);     // RNE
    return (ushort)(u >> 16);
}

// tanh-form gelu: x * sigmoid(1.59577x + 0.0713548x^3), max abs err ~1e-3
__device__ __forceinline__ float gelu_fast(float x) {
    float x2 = x * x;
    float y  = x * fmaf(0.0713548162726f, x2, 1.59576912161f);
    float e  = __expf(-y);
    return x * __builtin_amdgcn_rcpf(1.0f + e);
}

__device__ __forceinline__ ushort8v pack8(float4 lo, float4 hi) {
    ushort8v u;
    u[0] = f2bf(lo.x); u[1] = f2bf(lo.y); u[2] = f2bf(lo.z); u[3] = f2bf(lo.w);
    u[4] = f2bf(hi.x); u[5] = f2bf(hi.y); u[6] = f2bf(hi.z); u[7] = f2bf(hi.w);
    return u;
}

// ---------------------------------------------------------------------------
// W transpose pack: Wt[s][o*9 + kh*3 + kw][ci] = bf16(W[o][s*256+ci][kh][kw])
// One block per o. Reads 18KB coalesced, writes 9.2KB coalesced via LDS.
// ---------------------------------------------------------------------------
__global__ __launch_bounds__(256) void tc_pack_w(
    const float* __restrict__ W, ushort* __restrict__ Wt)
{
    const int o = blockIdx.x, t = threadIdx.x;
    __shared__ ushort lw[4608];          // W[o][:][:][:] as bf16, layout [c512][r9]
    const float* src = W + (size_t)o * 4608;
    #pragma unroll
    for (int i = 0; i < 18; ++i)
        lw[t + i * 256] = f2bf(src[t + i * 256]);
    __syncthreads();
    #pragma unroll
    for (int i = 0; i < 18; ++i) {
        int e   = t + i * 256;           // 0..4607
        int row = e >> 8;                // 0..17 = s*9 + r
        int c   = e & 255;
        int s   = (row >= 9);
        int r   = row - s * 9;           // kh*3+kw
        Wt[((size_t)s * NO + o * 9 + r) * C_ + c] = lw[((s << 8) + c) * 9 + r];
    }
}

// ---------------------------------------------------------------------------
// GEMM: G[s][n][m] = sum_k x_s[m][k] * Wt[s][n][k]   (bf16 MFMA, f32 out)
// 64x64 tile, 4 waves (2x2 of 32x32), full K=256 in two 128-halves.
// Phase-1 globals prefetched into registers during phase-0 staging.
// ---------------------------------------------------------------------------
__global__ __launch_bounds__(256) void tc_gemm(
    const float* __restrict__ x1, const float* __restrict__ x2,
    const ushort* __restrict__ Wt, float* __restrict__ G)
{
    const int tn = blockIdx.x;           // 0..35
    const int tm = blockIdx.y;           // 0..15
    const int s  = blockIdx.z;           // side

    __shared__ ushort As[64 * LDP];
    __shared__ ushort Bs[64 * LDP];

    const int tid = threadIdx.x;
    const int r   = tid & 63;            // staging row (one lane per row)
    const int q   = tid >> 6;            // wave id == staging k-quarter

    const float*  Xr = (s ? x2 : x1) + ((size_t)(tm * 64 + r)) * C_ + q * 32;
    const ushort* Wr = Wt + ((size_t)s * NO + tn * 64 + r) * C_ + q * 32;

    // ---- load phase 0 (k 0..127) and prefetch phase 1 (k 128..255)
    float4 al0[8], al1[8];
    ushort8v bl0[4], bl1[4];
    #pragma unroll
    for (int i = 0; i < 8; ++i) al0[i] = *(const float4*)(Xr + i * 4);
    #pragma unroll
    for (int i = 0; i < 4; ++i) bl0[i] = *(const ushort8v*)(Wr + i * 8);
    #pragma unroll
    for (int i = 0; i < 8; ++i) al1[i] = *(const float4*)(Xr + 128 + i * 4);
    #pragma unroll
    for (int i = 0; i < 4; ++i) bl1[i] = *(const ushort8v*)(Wr + 128 + i * 8);

    const int st = r * LDP + q * 32;     // staging LDS offset (ushorts)
    #pragma unroll
    for (int c = 0; c < 4; ++c) {
        *(ushort8v*)&As[st + c * 8] = pack8(al0[2 * c], al0[2 * c + 1]);
        *(ushort8v*)&Bs[st + c * 8] = bl0[c];
    }
    __syncthreads();

    const int wr  = q >> 1, wc = q & 1;
    const int r16 = tid & 15, kb = (tid & 63) >> 4;
    const int ar  = (wr * 32 + r16) * LDP + kb * 8;
    const int br  = (wc * 32 + r16) * LDP + kb * 8;

    f32x4 acc[2][2] = {};
    #pragma unroll
    for (int ks = 0; ks < 4; ++ks) {
        bf16x8 a0 = __builtin_bit_cast(bf16x8, *(const ushort8v*)&As[ar + ks * 32]);
        bf16x8 a1 = __builtin_bit_cast(bf16x8, *(const ushort8v*)&As[ar + 16 * LDP + ks * 32]);
        bf16x8 b0 = __builtin_bit_cast(bf16x8, *(const ushort8v*)&Bs[br + ks * 32]);
        bf16x8 b1 = __builtin_bit_cast(bf16x8, *(const ushort8v*)&Bs[br + 16 * LDP + ks * 32]);
        acc[0][0] = __builtin_amdgcn_mfma_f32_16x16x32_bf16(a0, b0, acc[0][0], 0, 0, 0);
        acc[0][1] = __builtin_amdgcn_mfma_f32_16x16x32_bf16(a0, b1, acc[0][1], 0, 0, 0);
        acc[1][0] = __builtin_amdgcn_mfma_f32_16x16x32_bf16(a1, b0, acc[1][0], 0, 0, 0);
        acc[1][1] = __builtin_amdgcn_mfma_f32_16x16x32_bf16(a1, b1, acc[1][1], 0, 0, 0);
    }
    __syncthreads();

    #pragma unroll
    for (int c = 0; c < 4; ++c) {
        *(ushort8v*)&As[st + c * 8] = pack8(al1[2 * c], al1[2 * c + 1]);
        *(ushort8v*)&Bs[st + c * 8] = bl1[c];
    }
    __syncthreads();

    #pragma unroll
    for (int ks = 0; ks < 4; ++ks) {
        bf16x8 a0 = __builtin_bit_cast(bf16x8, *(const ushort8v*)&As[ar + ks * 32]);
        bf16x8 a1 = __builtin_bit_cast(bf16x8, *(const ushort8v*)&As[ar + 16 * LDP + ks * 32]);
        bf16x8 b0 = __builtin_bit_cast(bf16x8, *(const ushort8v*)&Bs[br + ks * 32]);
        bf16x8 b1 = __builtin_bit_cast(bf16x8, *(const ushort8v*)&Bs[br + 16 * LDP + ks * 32]);
        acc[0][0] = __builtin_amdgcn_mfma_f32_16x16x32_bf16(a0, b0, acc[0][0], 0, 0, 0);
        acc[0][1] = __builtin_amdgcn_mfma_f32_16x16x32_bf16(a0, b1, acc[0][1], 0, 0, 0);
        acc[1][0] = __builtin_amdgcn_mfma_f32_16x16x32_bf16(a1, b0, acc[1][0], 0, 0, 0);
        acc[1][1] = __builtin_amdgcn_mfma_f32_16x16x32_bf16(a1, b1, acc[1][1], 0, 0, 0);
    }

    // store G[s][n][m]; D layout: col(n)=l&15, row(m)=(l>>4)*4+reg
    #pragma unroll
    for (int j = 0; j < 2; ++j) {
        int n = tn * 64 + wc * 32 + j * 16 + r16;
        #pragma unroll
        for (int i = 0; i < 2; ++i) {
            int m = tm * 64 + wr * 32 + i * 16 + kb * 4;
            *(f32x4*)&G[((size_t)s * NO + n) * M_ + m] = acc[i][j];
        }
    }
}

// ---------------------------------------------------------------------------
// Finalize: per (b,o) block, 128 threads = t.
// a_kw(t1) = sum_{valid kh} G0[o*9+kh*3+kw][b*128 + t1+kh-1]
// b_kh(t2) = sum_{valid kw} G1[o*9+kh*3+kw][b*128 + t2+kw-1]
// then the separable gelu-mean as before.
// ---------------------------------------------------------------------------
__global__ __launch_bounds__(128) void tc_finalize(
    const float* __restrict__ G, const float* __restrict__ x1,
    const float* __restrict__ bias, const float* __restrict__ alpha_p,
    float* __restrict__ out)
{
    const int o = blockIdx.x & 255;
    const int b = blockIdx.x >> 8;
    const int t = threadIdx.x;

    __shared__ float Bs3[T_], BsT[T_], BsB[T_];

    const float* G0 = G + ((size_t)o * 9) * M_ + b * T_;
    const float* G1 = G + ((size_t)NO + o * 9) * M_ + b * T_;

    float a[3] = {0.f, 0.f, 0.f};
    #pragma unroll
    for (int kh = 0; kh < 3; ++kh) {
        int tm = t + kh - 1;
        if (tm >= 0 && tm < T_) {
            #pragma unroll
            for (int kw = 0; kw < 3; ++kw)
                a[kw] += G0[(kh * 3 + kw) * M_ + tm];
        }
    }
    float bb[3] = {0.f, 0.f, 0.f};
    #pragma unroll
    for (int kw = 0; kw < 3; ++kw) {
        int tm = t + kw - 1;
        if (tm >= 0 && tm < T_) {
            #pragma unroll
            for (int kh = 0; kh < 3; ++kh)
                bb[kh] += G1[(kh * 3 + kw) * M_ + tm];
        }
    }

    Bs3[t] = bb[0] + bb[1] + bb[2];   // interior t1 (all kh)
    BsT[t] = bb[1] + bb[2];           // t1 == 0
    BsB[t] = bb[0] + bb[1];           // t1 == T-1

    float bo = bias[o];
    float A3 = bo + a[0] + a[1] + a[2];   // interior t2 (all kw)
    float Al = bo + a[1] + a[2];          // t2 == 0
    float Ar = bo + a[0] + a[1];          // t2 == T-1

    __syncthreads();

    const float* Bsel = (t == 0) ? BsT : ((t == T_ - 1) ? BsB : Bs3);

    float s0 = 0.f, s1 = 0.f, s2 = 0.f, s3 = 0.f;
    for (int j = 0; j < T_; j += 4) {
        s0 += gelu_fast(A3 + Bsel[j]);
        s1 += gelu_fast(A3 + Bsel[j + 1]);
        s2 += gelu_fast(A3 + Bsel[j + 2]);
        s3 += gelu_fast(A3 + Bsel[j + 3]);
    }
    float sacc = (s0 + s1) + (s2 + s3);
    sacc += gelu_fast(Al + Bsel[0])      - gelu_fast(A3 + Bsel[0]);
    sacc += gelu_fast(Ar + Bsel[T_ - 1]) - gelu_fast(A3 + Bsel[T_ - 1]);

    float alpha = *alpha_p;
    size_t oi = ((size_t)b * T_ + t) * C_ + o;
    out[oi] = sacc * (alpha * (1.0f / (float)T_)) + x1[oi];
}

extern "C" void kernel_launch(void* const* d_in, const int* in_sizes, int n_in,
                              void* d_out, int out_size, void* d_ws, size_t ws_size,
                              hipStream_t stream) {
    const float* x1    = (const float*)d_in[0];
    const float* x2    = (const float*)d_in[1];
    const float* W     = (const float*)d_in[2];
    const float* bias  = (const float*)d_in[3];
    const float* alpha = (const float*)d_in[4];
    float* out = (float*)d_out;

    // ws: G f32 [2][2304][1024] = 18.87 MB | Wt bf16 [2][2304][256] = 2.36 MB
    float*  G  = (float*)d_ws;
    ushort* Wt = (ushort*)((char*)d_ws + (size_t)2 * NO * M_ * 4);

    tc_pack_w<<<256, 256, 0, stream>>>(W, Wt);
    tc_gemm<<<dim3(NO / 64, M_ / 64, 2), 256, 0, stream>>>(x1, x2, Wt, G);
    tc_finalize<<<B_ * C_, T_, 0, stream>>>(G, x1, bias, alpha, out);
}

// Round 4
// 91.461 us; speedup vs baseline: 1.1442x; 1.1442x over previous
//
#include <hip/hip_runtime.h>
#include <math.h>

#define B_   8
#define T_   128
#define C_   256
#define XLDP 136       // staged X/W LDS row stride (ushorts): 128 + 8 pad
#define SLDP 82        // S LDS row stride (ushorts): 81-ish, even, 2-way-free

// LDS byte offsets (regions overlap across barrier-separated phases)
#define OFF_WS 34816   // Xs = [0, 34816) = 128*136*2 ; Ws 80*136*2 = 21760 -> end 56576
#define OFF_S1 20992   // S0 = [0, 20992) = 128*82*2 ; S1 -> end 41984
#define OFF_BV 41984   // Bv f32 [8][3][128] = 12288 -> end 54272
#define OFF_LO 54272   // Lout f32 [128][9] = 4608  -> end 58880
#define SMEMB  58880

typedef unsigned short ushort;
typedef ushort ushort8v __attribute__((ext_vector_type(8)));
typedef __bf16 bf16x8  __attribute__((ext_vector_type(8)));
typedef float  f32x4   __attribute__((ext_vector_type(4)));
typedef float  f32x2   __attribute__((ext_vector_type(2)));

__device__ __forceinline__ ushort f2bf(float f) {
    unsigned u = __float_as_uint(f);
    u += 0x7fffu + ((u >> 16) & 1u);     // RNE
    return (ushort)(u >> 16);
}
__device__ __forceinline__ float bf2f(ushort u) {
    return __uint_as_float((unsigned)u << 16);
}

// gelu ~ x * sigmoid(1.59577x + 0.0713548x^3); exp folded to exp2 (v_exp_f32)
__device__ __forceinline__ float gelu_fast(float x) {
    float x2 = x * x;
    float y2 = x * fmaf(0.10294324f, x2, 2.3022082f);   // y * log2(e)
    float e  = exp2f(-y2);
    return x * __builtin_amdgcn_rcpf(1.0f + e);
}

// ---------------------------------------------------------------------------
// Pack: W -> Wt bf16 [s][o][r][ci] (r = kh*3+kw; s=1 swaps kh/kw roles),
//       x1,x2 -> Xp bf16 [s][m][ci]  (m = b*128+t)
// ---------------------------------------------------------------------------
__global__ __launch_bounds__(256) void tc_pack(
    const float* __restrict__ x1, const float* __restrict__ x2,
    const float* __restrict__ W, ushort* __restrict__ Xp,
    ushort* __restrict__ Wt)
{
    const int bid = blockIdx.x, t = threadIdx.x;
    if (bid < 256) {                         // ---- W pack, one block per o
        __shared__ ushort lw[4608];          // [ch 512][r 9]
        const float* src = W + (size_t)bid * 4608;
        #pragma unroll
        for (int i = 0; i < 18; ++i)
            lw[t + i * 256] = f2bf(src[t + i * 256]);
        __syncthreads();
        #pragma unroll
        for (int i = 0; i < 18; ++i) {
            int d = t + i * 256;             // 0..4607
            int c = d & 255;
            int row18 = d >> 8;              // s*9 + r_out
            int s = (row18 >= 9) ? 1 : 0;
            int r = row18 - s * 9;           // for s=0: kh*3+kw ; s=1 we need r=kh*3+kw too
            // s=0: value W[o][c][r9]; s=1: want Wt[...][kh*3+kw][c] = W[o][256+c][kh*3+kw]
            // (both sides read lw at the SAME r = kh*3+kw index; the kh/kw ROLE swap
            //  happens in how the fused kernel applies shifts, with r reinterpreted)
            // side 1 needs r' = kw*3+kh when indexed by (tapshift=kw, other=kh):
            int rsrc = (s == 0) ? r : ((r % 3) * 3 + (r / 3));  // transpose 3x3 for side 1
            Wt[(((size_t)s * 256 + bid) * 9 + r) * 256 + c] = lw[(s * 256 + c) * 9 + rsrc];
        }
    } else {                                 // ---- X pack
        int g = (bid - 256) * 256 + t;       // chunk of 8 ushorts
        int e = g * 8;
        int s  = e >> 18;
        int me = e & 262143;
        int m  = me >> 8, c = me & 255;
        const float* src = (s ? x2 : x1) + (size_t)m * 256 + c;
        float4 lo = *(const float4*)src;
        float4 hi = *(const float4*)(src + 4);
        ushort8v u;
        u[0] = f2bf(lo.x); u[1] = f2bf(lo.y); u[2] = f2bf(lo.z); u[3] = f2bf(lo.w);
        u[4] = f2bf(hi.x); u[5] = f2bf(hi.y); u[6] = f2bf(hi.z); u[7] = f2bf(hi.w);
        *(ushort8v*)&Xp[e] = u;
    }
}

// ---------------------------------------------------------------------------
// Fused: per block (b, og): GEMM S_s[m][n] = sum_k X_s[b*128+m][k]*Wt[s][og*8..][n][k]
// (n = oo*9 + tapA*3 + tapB, side-1 pre-transposed so tapA is the SHIFT tap),
// then shift-recombination + gelu + mean + residual, all in LDS.
// Convention (matches verified rounds 1-3):
//   side 0: shift tap = kh (applies to t1), free tap = kw (selected by t2 class)
//   side 1: shift tap = kw (applies to t2), free tap = kh (selected by t1 class)
//   With the 3x3 transpose in tc_pack, BOTH sides use n = oo*9 + shift*3 + free.
// ---------------------------------------------------------------------------
__global__ __launch_bounds__(512) void tc_fused(
    const ushort* __restrict__ Xp, const ushort* __restrict__ Wt,
    const float* __restrict__ x1, const float* __restrict__ bias,
    const float* __restrict__ alpha_p, float* __restrict__ out)
{
    __shared__ __align__(16) char smem[SMEMB];
    ushort* Xs = (ushort*)smem;
    ushort* Ws = (ushort*)(smem + OFF_WS);
    float*  Bv = (float*)(smem + OFF_BV);
    float*  Lo = (float*)(smem + OFF_LO);

    const int u  = threadIdx.x;
    const int b  = blockIdx.x >> 5;
    const int og = blockIdx.x & 31;
    const int l  = u & 63, w = u >> 6;       // wave id 0..7
    const int r16 = l & 15, kb = l >> 4;

    const int xrow = u >> 2, xcb = (u & 3) * 32;
    const ushort* Xrow0 = Xp + ((size_t)(b * T_ + xrow)) * C_ + xcb;
    const ushort* WtB   = Wt + ((size_t)og * 72) * C_;

    f32x4 acc[2][5] = {};
    ushort8v xbuf[2][4];
    ushort8v wbuf[2][3];

    // preload round 0 (side 0, k-half 0)
    #pragma unroll
    for (int c4 = 0; c4 < 4; ++c4) xbuf[0][c4] = *(const ushort8v*)(Xrow0 + c4 * 8);
    {
        int c0 = u;          int r0 = c0 >> 4, o0 = (c0 & 15) * 8;
        int c1 = 512 + u;    int r1 = c1 >> 4, o1 = (c1 & 15) * 8;
        wbuf[0][0] = *(const ushort8v*)(WtB + (size_t)r0 * C_ + o0);
        wbuf[0][1] = *(const ushort8v*)(WtB + (size_t)r1 * C_ + o1);
        if (u < 128) {
            int c2 = 1024 + u; int r2 = c2 >> 4, o2 = (c2 & 15) * 8;
            wbuf[0][2] = *(const ushort8v*)(WtB + (size_t)r2 * C_ + o2);
        }
    }

    #pragma unroll
    for (int r = 0; r < 4; ++r) {
        const int cur = r & 1;
        __syncthreads();                     // prior round's frag reads done
        #pragma unroll
        for (int c4 = 0; c4 < 4; ++c4)
            *(ushort8v*)&Xs[xrow * XLDP + xcb + c4 * 8] = xbuf[cur][c4];
        {
            int c0 = u;       *(ushort8v*)&Ws[(c0 >> 4) * XLDP + (c0 & 15) * 8] = wbuf[cur][0];
            int c1 = 512 + u; *(ushort8v*)&Ws[(c1 >> 4) * XLDP + (c1 & 15) * 8] = wbuf[cur][1];
            if (u < 128) {
                int c2 = 1024 + u;
                *(ushort8v*)&Ws[(c2 >> 4) * XLDP + (c2 & 15) * 8] = wbuf[cur][2];
            }
        }
        if (r < 3) {                         // prefetch next round into other buf
            const int rn = r + 1, sn = rn >> 1, pn = rn & 1;
            const ushort* xsrc = Xrow0 + (size_t)sn * 262144 + pn * 128;
            #pragma unroll
            for (int c4 = 0; c4 < 4; ++c4)
                xbuf[cur ^ 1][c4] = *(const ushort8v*)(xsrc + c4 * 8);
            const ushort* wsrc = WtB + (size_t)sn * 2304 * C_ + pn * 128;
            int c0 = u;       wbuf[cur ^ 1][0] = *(const ushort8v*)(wsrc + (size_t)(c0 >> 4) * C_ + (c0 & 15) * 8);
            int c1 = 512 + u; wbuf[cur ^ 1][1] = *(const ushort8v*)(wsrc + (size_t)(c1 >> 4) * C_ + (c1 & 15) * 8);
            if (u < 128) {
                int c2 = 1024 + u;
                wbuf[cur ^ 1][2] = *(const ushort8v*)(wsrc + (size_t)(c2 >> 4) * C_ + (c2 & 15) * 8);
            }
        }
        __syncthreads();
        const int s = r >> 1;
        #pragma unroll
        for (int ks = 0; ks < 4; ++ks) {
            bf16x8 af = __builtin_bit_cast(bf16x8,
                *(const ushort8v*)&Xs[(w * 16 + r16) * XLDP + ks * 32 + kb * 8]);
            #pragma unroll
            for (int nf = 0; nf < 5; ++nf) {
                bf16x8 bf = __builtin_bit_cast(bf16x8,
                    *(const ushort8v*)&Ws[(nf * 16 + r16) * XLDP + ks * 32 + kb * 8]);
                acc[s][nf] = __builtin_amdgcn_mfma_f32_16x16x32_bf16(af, bf, acc[s][nf], 0, 0, 0);
            }
        }
    }
    __syncthreads();                          // all MFMA frag reads done; reuse LDS

    // ---- write S (bf16): D layout m = w*16 + kb*4 + reg, n = nf*16 + r16
    #pragma unroll
    for (int s = 0; s < 2; ++s) {
        ushort* Sb = (ushort*)(smem + (s ? OFF_S1 : 0));
        #pragma unroll
        for (int nf = 0; nf < 5; ++nf) {
            int n = nf * 16 + r16;
            if (n < 72) {
                #pragma unroll
                for (int reg = 0; reg < 4; ++reg) {
                    int m = w * 16 + kb * 4 + reg;
                    Sb[m * SLDP + n] = f2bf(acc[s][nf][reg]);
                }
            }
        }
    }
    __syncthreads();

    // ---- recombination: thread u -> oo = u>>6 (== w), t in {u&63, (u&63)+64}
    const int oo  = w;
    const int t0  = l;
    const int o_g = og * 8 + oo;
    const float bo = bias[o_g];
    const ushort* S0 = (const ushort*)smem;
    const ushort* S1 = (const ushort*)(smem + OFF_S1);
    float A3[2], Al[2], Ar[2];
    #pragma unroll
    for (int idx = 0; idx < 2; ++idx) {
        int tt = t0 + idx * 64;
        float a0 = 0.f, a1 = 0.f, a2 = 0.f;          // indexed by free tap (kw)
        #pragma unroll
        for (int sh = 0; sh < 3; ++sh) {             // shift tap (kh), applies to t1
            int row = tt + sh - 1;
            if (row >= 0 && row < T_) {
                int base = row * SLDP + oo * 9 + sh * 3;
                a0 += bf2f(S0[base]); a1 += bf2f(S0[base + 1]); a2 += bf2f(S0[base + 2]);
            }
        }
        A3[idx] = bo + a0 + a1 + a2;                 // interior t2
        Al[idx] = bo + a1 + a2;                      // t2 == 0   (kw=0 invalid)
        Ar[idx] = bo + a0 + a1;                      // t2 == T-1 (kw=2 invalid)
        float b0 = 0.f, b1 = 0.f, b2 = 0.f;          // indexed by free tap (kh)
        #pragma unroll
        for (int sh = 0; sh < 3; ++sh) {             // shift tap (kw), applies to t2
            int row = tt + sh - 1;
            if (row >= 0 && row < T_) {
                int base = row * SLDP + oo * 9 + sh * 3;
                b0 += bf2f(S1[base]); b1 += bf2f(S1[base + 1]); b2 += bf2f(S1[base + 2]);
            }
        }
        Bv[(oo * 3 + 0) * T_ + tt] = b0 + b1 + b2;   // interior t1
        Bv[(oo * 3 + 1) * T_ + tt] = b1 + b2;        // t1 == 0   (kh=0 invalid)
        Bv[(oo * 3 + 2) * T_ + tt] = b0 + b1;        // t1 == T-1 (kh=2 invalid)
    }
    __syncthreads();

    // ---- gelu-mean
    #pragma unroll
    for (int idx = 0; idx < 2; ++idx) {
        int tt  = t0 + idx * 64;
        int cls = (tt == 0) ? 1 : ((tt == T_ - 1) ? 2 : 0);
        const float* Bs = Bv + (oo * 3 + cls) * T_;
        float A = A3[idx];
        float s0 = 0.f, s1 = 0.f, s2 = 0.f, s3 = 0.f;
        for (int j = 0; j < T_; j += 4) {
            f32x4 v = *(const f32x4*)&Bs[j];
            s0 += gelu_fast(A + v[0]); s1 += gelu_fast(A + v[1]);
            s2 += gelu_fast(A + v[2]); s3 += gelu_fast(A + v[3]);
        }
        float sm = (s0 + s1) + (s2 + s3);
        float bl = Bs[0], br = Bs[T_ - 1];
        sm += gelu_fast(Al[idx] + bl) - gelu_fast(A + bl);
        sm += gelu_fast(Ar[idx] + br) - gelu_fast(A + br);
        Lo[tt * 9 + oo] = sm;
    }
    __syncthreads();

    // ---- transposed coalesced writeout with residual
    const float kk = (*alpha_p) * (1.0f / (float)T_);
    {
        int row = u >> 2, c2 = (u & 3) * 2;
        size_t go = ((size_t)(b * T_ + row)) * C_ + og * 8 + c2;
        f32x2 r;
        r[0] = Lo[row * 9 + c2]     * kk + x1[go];
        r[1] = Lo[row * 9 + c2 + 1] * kk + x1[go + 1];
        *(f32x2*)&out[go] = r;
    }
}

extern "C" void kernel_launch(void* const* d_in, const int* in_sizes, int n_in,
                              void* d_out, int out_size, void* d_ws, size_t ws_size,
                              hipStream_t stream) {
    const float* x1    = (const float*)d_in[0];
    const float* x2    = (const float*)d_in[1];
    const float* W     = (const float*)d_in[2];
    const float* bias  = (const float*)d_in[3];
    const float* alpha = (const float*)d_in[4];
    float* out = (float*)d_out;

    // ws: Xp bf16 [2][1024][256] = 1.05 MB | Wt bf16 [2][256][9][256] = 2.36 MB
    ushort* Xp = (ushort*)d_ws;
    ushort* Wt = Xp + (size_t)2 * 1024 * 256;

    tc_pack<<<512, 256, 0, stream>>>(x1, x2, W, Xp, Wt);
    tc_fused<<<256, 512, 0, stream>>>(Xp, Wt, x1, bias, alpha, out);
}